// Round 1
// 298.395 us; speedup vs baseline: 1.0210x; 1.0210x over previous
//
#include <hip/hip_runtime.h>
#include <hip/hip_bf16.h>
#include <math.h>

// Problem constants
#define S_LEN 1024
#define HDIM  2880
#define NH    64
#define NKV   8
#define HD    64
#define QKV_N ((NH + 2*NKV) * HD)   // 5120
#define O_K   (NH * HD)             // 4096
#define SCALE 0.125f                // HD^-0.5

typedef _Float16 f16x8 __attribute__((ext_vector_type(8)));
typedef _Float16 f16x4 __attribute__((ext_vector_type(4)));
typedef float    f32x4 __attribute__((ext_vector_type(4)));

// ---------------------------------------------------------------------------
// f32 -> f16 convert (generic; n4 = float4 count)
// ---------------------------------------------------------------------------
__device__ __forceinline__ void cvt4(const float* __restrict__ s,
                                     _Float16* __restrict__ d, int i) {
    const float4 v = ((const float4*)s)[i];
    f16x4 p;
    p[0] = (_Float16)v.x; p[1] = (_Float16)v.y;
    p[2] = (_Float16)v.z; p[3] = (_Float16)v.w;
    ((f16x4*)d)[i] = p;
}

__global__ __launch_bounds__(256) void cvt_f32_f16(const float* __restrict__ src,
                                                   _Float16* __restrict__ dst, int n4) {
    const int stride = gridDim.x * blockDim.x;
    for (int i = blockIdx.x * blockDim.x + threadIdx.x; i < n4; i += stride)
        cvt4(src, dst, i);
}

// One pass: hidden (737280 f4) + qkv_w (3686400 f4) + o_w (2949120 f4)
__global__ __launch_bounds__(256) void cvt_all(const float* __restrict__ h,
                                               const float* __restrict__ qw,
                                               const float* __restrict__ ow,
                                               _Float16* __restrict__ dh,
                                               _Float16* __restrict__ dqw,
                                               _Float16* __restrict__ dow) {
    const int stride = gridDim.x * blockDim.x;
    const int t0 = blockIdx.x * blockDim.x + threadIdx.x;
    for (int i = t0; i < 737280;  i += stride) cvt4(h,  dh,  i);
    for (int i = t0; i < 3686400; i += stride) cvt4(qw, dqw, i);
    for (int i = t0; i < 2949120; i += stride) cvt4(ow, dow, i);
}

// ---------------------------------------------------------------------------
// Pure-f16 split-K MFMA GEMM: both operands staged via global_load_lds
// (width 16), 128x128 tile, BK=32, double-buffered, single barrier / step
// (m97 structure). C[z][M,N] = A[M,Kslice] * B[N,Kslice]^T.
// ---------------------------------------------------------------------------
#define CSTR 68

#define DMA16(GP, LP) __builtin_amdgcn_global_load_lds( \
        (const __attribute__((address_space(1))) void*)(GP), \
        (__attribute__((address_space(3))) void*)(LP), 16, 0, 0)

template<typename CT>
__global__ __launch_bounds__(256) void gemm_ff(const _Float16* __restrict__ A,
                                               const _Float16* __restrict__ B,
                                               CT* __restrict__ C,
                                               int M, int N, int K) {
    __shared__ __align__(16) _Float16 sh[16384];   // 32 KB: As0|As1|Bs0|Bs1

    const int tid  = threadIdx.x;
    const int lane = tid & 63;
    const int wave = tid >> 6;
    const int wr   = wave >> 1;
    const int wc   = wave & 1;
    const int quad = lane >> 4;
    const int fr   = lane & 15;
    const int ks   = quad * 8;
    const int row0 = blockIdx.y * 128;
    const int col0 = blockIdx.x * 128;

    const int klen   = K / (int)gridDim.z;
    const int kb     = (int)blockIdx.z * klen;
    const int nsteps = klen / 32;
    CT* Cp = C + (size_t)blockIdx.z * M * N;

    // DMA chunk mapping: chunk c in [0,512): row = c>>2, 8-f16 group (c&3).
    // Thread handles chunks tid and tid+256. LDS dest = wave-uniform base
    // (hardware adds lane*16).
    const int r0   = tid >> 2;          // rows 0..63 (chunk tid)
    const int ch   = (tid & 3) * 8;     // k-offset in f16
    const int dst0 = (tid & ~63) * 8;   // f16 offset of wave-uniform LDS base

    const size_t aoff0 = (size_t)(row0 + r0)      * K;
    const size_t aoff1 = (size_t)(row0 + r0 + 64) * K;
    int bR0 = col0 + r0;      if (bR0 >= N) bR0 = N - 1;
    int bR1 = col0 + r0 + 64; if (bR1 >= N) bR1 = N - 1;
    const size_t boff0 = (size_t)bR0 * K;
    const size_t boff1 = (size_t)bR1 * K;

    f32x4 acc[4][4] = {};

    // ---- prologue: stage tile 0 into buffers 0 ----
    {
        const int kk = kb + ch;
        DMA16(A + aoff0 + kk, sh + dst0);
        DMA16(A + aoff1 + kk, sh + 2048 + dst0);
        DMA16(B + boff0 + kk, sh + 8192 + dst0);
        DMA16(B + boff1 + kk, sh + 8192 + 2048 + dst0);
    }

    for (int step = 0; step < nsteps; ++step) {
        const int cur = step & 1;
        _Float16* Acur = sh + cur * 4096;
        _Float16* Anxt = sh + (cur ^ 1) * 4096;
        _Float16* Bcur = sh + 8192 + cur * 4096;
        _Float16* Bnxt = sh + 8192 + (cur ^ 1) * 4096;

        __syncthreads();   // tile[cur] staged (barrier drains vmcnt)

        if (step + 1 < nsteps) {
            const int k1 = kb + (step + 1) * 32 + ch;
            DMA16(A + aoff0 + k1, Anxt + dst0);
            DMA16(A + aoff1 + k1, Anxt + 2048 + dst0);
            DMA16(B + boff0 + k1, Bnxt + dst0);
            DMA16(B + boff1 + k1, Bnxt + 2048 + dst0);
        }

        // ---- compute tile[cur] ----
        f16x8 af[4], bf[4];
#pragma unroll
        for (int mi = 0; mi < 4; ++mi)
            af[mi] = *(const f16x8*)&Acur[(wr * 64 + mi * 16 + fr) * 32 + ks];
#pragma unroll
        for (int ni = 0; ni < 4; ++ni)
            bf[ni] = *(const f16x8*)&Bcur[(wc * 64 + ni * 16 + fr) * 32 + ks];
#pragma unroll
        for (int mi = 0; mi < 4; ++mi)
#pragma unroll
            for (int ni = 0; ni < 4; ++ni)
                acc[mi][ni] = __builtin_amdgcn_mfma_f32_16x16x32_f16(
                    af[mi], bf[ni], acc[mi][ni], 0, 0, 0);
    }

    // ---- epilogue via LDS: 2 passes over column halves, coalesced stores ----
#pragma unroll
    for (int p = 0; p < 2; ++p) {
        __syncthreads();
        if (wc == p) {
#pragma unroll
            for (int mi = 0; mi < 4; ++mi)
#pragma unroll
                for (int ni = 0; ni < 4; ++ni) {
                    const f32x4 v = acc[mi][ni];
#pragma unroll
                    for (int r = 0; r < 4; ++r)
                        sh[(wr * 64 + mi * 16 + quad * 4 + r) * CSTR + ni * 16 + fr] =
                            (_Float16)v[r];
                }
        }
        __syncthreads();
#pragma unroll
        for (int it = 0; it < 4; ++it) {
            const int id  = it * 256 + tid;
            const int row = id >> 3;
            const int chh = (id & 7) * 8;
            const int col = col0 + p * 64 + chh;
            if (col < N) {
                const f16x4 lo = *(const f16x4*)&sh[row * CSTR + chh];
                const f16x4 hi = *(const f16x4*)&sh[row * CSTR + chh + 4];
                if constexpr (sizeof(CT) == 2) {
                    f16x8 v;
                    v[0]=lo[0]; v[1]=lo[1]; v[2]=lo[2]; v[3]=lo[3];
                    v[4]=hi[0]; v[5]=hi[1]; v[6]=hi[2]; v[7]=hi[3];
                    *(f16x8*)&Cp[(size_t)(row0 + row) * N + col] = v;
                } else {
                    float4 v0 = make_float4((float)lo[0], (float)lo[1],
                                            (float)lo[2], (float)lo[3]);
                    float4 v1 = make_float4((float)hi[0], (float)hi[1],
                                            (float)hi[2], (float)hi[3]);
                    *(float4*)&Cp[(size_t)(row0 + row) * N + col]     = v0;
                    *(float4*)&Cp[(size_t)(row0 + row) * N + col + 4] = v1;
                }
            }
        }
    }
}

// ---------------------------------------------------------------------------
// Fallback GEMM (fused f32->f16 B conversion) — used only when workspace is
// too small for pre-converted weights. Unchanged from previous version.
// ---------------------------------------------------------------------------
template<typename CT>
__global__ __launch_bounds__(256) void gemm_f16(const _Float16* __restrict__ A,
                                                const float* __restrict__ B,
                                                CT* __restrict__ C,
                                                int M, int N, int K) {
    __shared__ __align__(16) _Float16 sh[16384];

    const int tid  = threadIdx.x;
    const int lane = tid & 63;
    const int wave = tid >> 6;
    const int wr   = wave >> 1;
    const int wc   = wave & 1;
    const int quad = lane >> 4;
    const int fr   = lane & 15;
    const int ks   = quad * 8;
    const int row0 = blockIdx.y * 128;
    const int col0 = blockIdx.x * 128;

    const int klen   = K / (int)gridDim.z;
    const int kb     = (int)blockIdx.z * klen;
    const int nsteps = klen / 32;
    CT* Cp = C + (size_t)blockIdx.z * M * N;

    const int a_cbase0 = wave * 64;
    const int a_ci0 = a_cbase0 + lane;
    const int a_r0 = a_ci0 >> 2, a_ch0 = a_ci0 & 3;
    const int a_cbase1 = 256 + wave * 64;
    const int a_ci1 = a_cbase1 + lane;
    const int a_r1 = a_ci1 >> 2, a_ch1 = a_ci1 & 3;
    int b_r[4], b_ch[4];
#pragma unroll
    for (int it = 0; it < 4; ++it) {
        const int c4 = it * 256 + tid;
        b_r[it]  = c4 >> 3;
        b_ch[it] = (c4 & 7) << 2;
    }

    float4 breg[4];
    f32x4 acc[4][4] = {};

    {
        const _Float16* gp0 = A + (size_t)(row0 + a_r0) * K + kb + a_ch0 * 8;
        DMA16(gp0, sh + (size_t)a_cbase0 * 8);
        const _Float16* gp1 = A + (size_t)(row0 + a_r1) * K + kb + a_ch1 * 8;
        DMA16(gp1, sh + (size_t)a_cbase1 * 8);
#pragma unroll
        for (int it = 0; it < 4; ++it) {
            int brow = col0 + b_r[it];
            if (brow >= N) brow = N - 1;
            breg[it] = *(const float4*)&B[(size_t)brow * K + kb + b_ch[it]];
        }
        _Float16* Bs0 = sh + 8192;
#pragma unroll
        for (int it = 0; it < 4; ++it) {
            f16x4 p;
            p[0] = (_Float16)breg[it].x; p[1] = (_Float16)breg[it].y;
            p[2] = (_Float16)breg[it].z; p[3] = (_Float16)breg[it].w;
            *(f16x4*)&Bs0[b_r[it] * 32 + b_ch[it]] = p;
        }
    }

    for (int step = 0; step < nsteps; ++step) {
        const int cur = step & 1;
        const int nxt = cur ^ 1;
        _Float16* Acur = sh + cur * 4096;
        _Float16* Anxt = sh + nxt * 4096;
        _Float16* Bcur = sh + 8192 + cur * 4096;
        _Float16* Bnxt = sh + 8192 + nxt * 4096;

        __syncthreads();

        const bool more = (step + 1 < nsteps);
        if (more) {
            const int k1 = kb + (step + 1) * 32;
            const _Float16* gp0 = A + (size_t)(row0 + a_r0) * K + k1 + a_ch0 * 8;
            DMA16(gp0, Anxt + (size_t)a_cbase0 * 8);
            const _Float16* gp1 = A + (size_t)(row0 + a_r1) * K + k1 + a_ch1 * 8;
            DMA16(gp1, Anxt + (size_t)a_cbase1 * 8);
#pragma unroll
            for (int it = 0; it < 4; ++it) {
                int brow = col0 + b_r[it];
                if (brow >= N) brow = N - 1;
                breg[it] = *(const float4*)&B[(size_t)brow * K + k1 + b_ch[it]];
            }
        }

        f16x8 af[4], bfr[4];
#pragma unroll
        for (int mi = 0; mi < 4; ++mi)
            af[mi] = *(const f16x8*)&Acur[(wr * 64 + mi * 16 + fr) * 32 + ks];
#pragma unroll
        for (int ni = 0; ni < 4; ++ni)
            bfr[ni] = *(const f16x8*)&Bcur[(wc * 64 + ni * 16 + fr) * 32 + ks];
#pragma unroll
        for (int mi = 0; mi < 4; ++mi)
#pragma unroll
            for (int ni = 0; ni < 4; ++ni)
                acc[mi][ni] = __builtin_amdgcn_mfma_f32_16x16x32_f16(
                    af[mi], bfr[ni], acc[mi][ni], 0, 0, 0);

        if (more) {
#pragma unroll
            for (int it = 0; it < 4; ++it) {
                f16x4 p;
                p[0] = (_Float16)breg[it].x; p[1] = (_Float16)breg[it].y;
                p[2] = (_Float16)breg[it].z; p[3] = (_Float16)breg[it].w;
                *(f16x4*)&Bnxt[b_r[it] * 32 + b_ch[it]] = p;
            }
        }
    }

#pragma unroll
    for (int p = 0; p < 2; ++p) {
        __syncthreads();
        if (wc == p) {
#pragma unroll
            for (int mi = 0; mi < 4; ++mi)
#pragma unroll
                for (int ni = 0; ni < 4; ++ni) {
                    const f32x4 v = acc[mi][ni];
#pragma unroll
                    for (int r = 0; r < 4; ++r)
                        sh[(wr * 64 + mi * 16 + quad * 4 + r) * CSTR + ni * 16 + fr] =
                            (_Float16)v[r];
                }
        }
        __syncthreads();
#pragma unroll
        for (int it = 0; it < 4; ++it) {
            const int id  = it * 256 + tid;
            const int row = id >> 3;
            const int chh = (id & 7) * 8;
            const int col = col0 + p * 64 + chh;
            if (col < N) {
                const f16x4 lo = *(const f16x4*)&sh[row * CSTR + chh];
                const f16x4 hi = *(const f16x4*)&sh[row * CSTR + chh + 4];
                if constexpr (sizeof(CT) == 2) {
                    f16x8 v;
                    v[0]=lo[0]; v[1]=lo[1]; v[2]=lo[2]; v[3]=lo[3];
                    v[4]=hi[0]; v[5]=hi[1]; v[6]=hi[2]; v[7]=hi[3];
                    *(f16x8*)&Cp[(size_t)(row0 + row) * N + col] = v;
                } else {
                    float4 v0 = make_float4((float)lo[0], (float)lo[1],
                                            (float)lo[2], (float)lo[3]);
                    float4 v1 = make_float4((float)hi[0], (float)hi[1],
                                            (float)hi[2], (float)hi[3]);
                    *(float4*)&Cp[(size_t)(row0 + row) * N + col]     = v0;
                    *(float4*)&Cp[(size_t)(row0 + row) * N + col + 4] = v1;
                }
            }
        }
    }
}

// ---------------------------------------------------------------------------
// Fused: sum nsplit f16 qkv partials -> rope q,k -> write f16 into partial 0;
// also emit V transposed as vt[d 512][s 1024]. One block per position.
// ---------------------------------------------------------------------------
__global__ __launch_bounds__(256) void rope_reduce(_Float16* __restrict__ parts,
                                                   int nsplit,
                                                   _Float16* __restrict__ vt,
                                                   const int* __restrict__ positions) {
    __shared__ float buf[QKV_N];   // 20 KB
    const int s   = blockIdx.x;
    const int tid = threadIdx.x;
    const size_t PSTR = (size_t)S_LEN * QKV_N;

    for (int c = tid; c < QKV_N / 4; c += 256) {
        float4 a = make_float4(0.f, 0.f, 0.f, 0.f);
        for (int j = 0; j < nsplit; ++j) {
            const f16x4 v = ((const f16x4*)(parts + j * PSTR + (size_t)s * QKV_N))[c];
            a.x += (float)v[0]; a.y += (float)v[1];
            a.z += (float)v[2]; a.w += (float)v[3];
        }
        ((float4*)buf)[c] = a;
    }
    __syncthreads();

    const float pos = (float)positions[s];
    _Float16* orow = parts + (size_t)s * QKV_N;   // write into partial 0
    for (int w = tid; w < 72 * 32; w += 256) {
        const int h = w >> 5;
        const int t = w & 31;
        const float inv_freq = exp2f(-(float)t * (13.287712379549449f / 32.0f));
        const float ang = pos * inv_freq;
        float sn, cs;
        sincosf(ang, &sn, &cs);
        const float x1 = buf[h * 64 + t];
        const float x2 = buf[h * 64 + t + 32];
        orow[h * 64 + t]      = (_Float16)(x1 * cs - x2 * sn);
        orow[h * 64 + t + 32] = (_Float16)(x2 * cs + x1 * sn);
    }
    // V -> vt (transposed), source cols 4608..5119
    for (int c = tid; c < NKV * HD; c += 256)
        vt[(size_t)c * S_LEN + s] = (_Float16)buf[(NH + NKV) * HD + c];
}

// ---------------------------------------------------------------------------
// o-proj partial reduce: out(f32) = sum of nsplit f16 partials
// ---------------------------------------------------------------------------
__global__ __launch_bounds__(256) void o_reduce(const _Float16* __restrict__ parts,
                                                float* __restrict__ out,
                                                int n4, int nsplit) {
    const size_t PSTR = (size_t)S_LEN * HDIM;
    const int stride = gridDim.x * blockDim.x;
    for (int i = blockIdx.x * blockDim.x + threadIdx.x; i < n4; i += stride) {
        float4 a = make_float4(0.f, 0.f, 0.f, 0.f);
        for (int j = 0; j < nsplit; ++j) {
            const f16x4 v = ((const f16x4*)(parts + j * PSTR))[i];
            a.x += (float)v[0]; a.y += (float)v[1];
            a.z += (float)v[2]; a.w += (float)v[3];
        }
        ((float4*)out)[i] = a;
    }
}

// ---------------------------------------------------------------------------
// MFMA flash attention, double-buffered K/V staging (single barrier / tile).
// ---------------------------------------------------------------------------
#define LSTR 72
__global__ __launch_bounds__(256) void attn_mfma(const _Float16* __restrict__ qkv,
                                                 const _Float16* __restrict__ vt,
                                                 const float* __restrict__ sinks,
                                                 const int* __restrict__ positions,
                                                 _Float16* __restrict__ attn_out) {
    __shared__ __align__(16) _Float16 Ks[2][64 * LSTR];
    __shared__ __align__(16) _Float16 Vs[2][64 * LSTR];
    __shared__ __align__(16) _Float16 Ps[64 * LSTR];

    const int tid  = threadIdx.x;
    const int lane = tid & 63;
    const int wave = tid >> 6;
    const int fr   = lane & 15;
    const int quad = lane >> 4;
    const int ks8  = quad * 8;
    const int n    = blockIdx.x;
    const int qt   = (int)gridDim.y - 1 - (int)blockIdx.y;   // heavy tiles first
    const int g    = n >> 3;

    int st_r[2], st_o[2];
#pragma unroll
    for (int it = 0; it < 2; ++it) {
        const int c = it * 256 + tid;
        st_r[it] = c >> 3;
        st_o[it] = (c & 7) * 8;
    }

    const _Float16* qrow = qkv + (size_t)(qt * 64 + wave * 16 + fr) * QKV_N + n * HD;
    const f16x8 a_q0 = *(const f16x8*)&qrow[ks8];
    const f16x8 a_q1 = *(const f16x8*)&qrow[32 + ks8];

    int pq[4];
#pragma unroll
    for (int r = 0; r < 4; ++r)
        pq[r] = positions[qt * 64 + wave * 16 + quad * 4 + r];

    const float sinkv = sinks[n];
    float m[4], l[4];
    f32x4 o[4] = {};
#pragma unroll
    for (int r = 0; r < 4; ++r) { m[r] = sinkv; l[r] = 1.0f; }

    f16x8 kreg[2], vreg[2];
    {
        const _Float16* Kg = qkv + (size_t)0 * QKV_N + NH * HD + g * HD;
        const _Float16* Vg = vt + (size_t)(g * HD) * S_LEN;
#pragma unroll
        for (int it = 0; it < 2; ++it) {
            kreg[it] = *(const f16x8*)&Kg[(size_t)st_r[it] * QKV_N + st_o[it]];
            vreg[it] = *(const f16x8*)&Vg[(size_t)st_r[it] * S_LEN + st_o[it]];
        }
#pragma unroll
        for (int it = 0; it < 2; ++it) {
            *(f16x8*)&Ks[0][st_r[it] * LSTR + st_o[it]] = kreg[it];
            *(f16x8*)&Vs[0][st_r[it] * LSTR + st_o[it]] = vreg[it];
        }
    }

    for (int kt = 0; kt <= qt; ++kt) {
        const int cur = kt & 1;
        const int nxt = cur ^ 1;
        __syncthreads();

        const bool more = (kt < qt);
        if (more) {
            const _Float16* Kg = qkv + (size_t)((kt + 1) * 64) * QKV_N + NH * HD + g * HD;
            const _Float16* Vg = vt + (size_t)(g * HD) * S_LEN + (kt + 1) * 64;
#pragma unroll
            for (int it = 0; it < 2; ++it) {
                kreg[it] = *(const f16x8*)&Kg[(size_t)st_r[it] * QKV_N + st_o[it]];
                vreg[it] = *(const f16x8*)&Vg[(size_t)st_r[it] * S_LEN + st_o[it]];
            }
        }

        f32x4 s[4] = {};
#pragma unroll
        for (int nt = 0; nt < 4; ++nt) {
            const f16x8 b0 = *(const f16x8*)&Ks[cur][(nt * 16 + fr) * LSTR + ks8];
            s[nt] = __builtin_amdgcn_mfma_f32_16x16x32_f16(a_q0, b0, s[nt], 0, 0, 0);
            const f16x8 b1 = *(const f16x8*)&Ks[cur][(nt * 16 + fr) * LSTR + 32 + ks8];
            s[nt] = __builtin_amdgcn_mfma_f32_16x16x32_f16(a_q1, b1, s[nt], 0, 0, 0);
        }

        const bool diag = (kt == qt);
        int pk[4];
        if (diag) {
#pragma unroll
            for (int nt = 0; nt < 4; ++nt) pk[nt] = positions[qt * 64 + nt * 16 + fr];
        }
#pragma unroll
        for (int nt = 0; nt < 4; ++nt)
#pragma unroll
            for (int r = 0; r < 4; ++r) {
                float sv = s[nt][r] * SCALE;
                if (diag && pk[nt] > pq[r]) sv = -3.0e38f;
                s[nt][r] = sv;
            }

#pragma unroll
        for (int r = 0; r < 4; ++r) {
            float tm = fmaxf(fmaxf(s[0][r], s[1][r]), fmaxf(s[2][r], s[3][r]));
            tm = fmaxf(tm, __shfl_xor(tm, 1, 64));
            tm = fmaxf(tm, __shfl_xor(tm, 2, 64));
            tm = fmaxf(tm, __shfl_xor(tm, 4, 64));
            tm = fmaxf(tm, __shfl_xor(tm, 8, 64));
            const float nm = fmaxf(m[r], tm);
            const float alpha = __expf(m[r] - nm);
            float rs = 0.0f;
#pragma unroll
            for (int nt = 0; nt < 4; ++nt) {
                const float p = __expf(s[nt][r] - nm);
                s[nt][r] = p;
                rs += p;
            }
            rs += __shfl_xor(rs, 1, 64);
            rs += __shfl_xor(rs, 2, 64);
            rs += __shfl_xor(rs, 4, 64);
            rs += __shfl_xor(rs, 8, 64);
            l[r] = l[r] * alpha + rs;
            m[r] = nm;
#pragma unroll
            for (int nt = 0; nt < 4; ++nt) o[nt][r] *= alpha;
        }

#pragma unroll
        for (int nt = 0; nt < 4; ++nt)
#pragma unroll
            for (int r = 0; r < 4; ++r)
                Ps[(wave * 16 + quad * 4 + r) * LSTR + nt * 16 + fr] = (_Float16)s[nt][r];
        __threadfence_block();

#pragma unroll
        for (int k2 = 0; k2 < 2; ++k2) {
            const f16x8 ap = *(const f16x8*)&Ps[(wave * 16 + fr) * LSTR + k2 * 32 + ks8];
#pragma unroll
            for (int nt = 0; nt < 4; ++nt) {
                const f16x8 bv = *(const f16x8*)&Vs[cur][(nt * 16 + fr) * LSTR + k2 * 32 + ks8];
                o[nt] = __builtin_amdgcn_mfma_f32_16x16x32_f16(ap, bv, o[nt], 0, 0, 0);
            }
        }

        if (more) {
#pragma unroll
            for (int it = 0; it < 2; ++it) {
                *(f16x8*)&Ks[nxt][st_r[it] * LSTR + st_o[it]] = kreg[it];
                *(f16x8*)&Vs[nxt][st_r[it] * LSTR + st_o[it]] = vreg[it];
            }
        }
    }

#pragma unroll
    for (int r = 0; r < 4; ++r) {
        const float inv = 1.0f / l[r];
        const size_t row = (size_t)(qt * 64 + wave * 16 + quad * 4 + r);
#pragma unroll
        for (int nt = 0; nt < 4; ++nt)
            attn_out[row * O_K + n * HD + nt * 16 + fr] = (_Float16)(o[nt][r] * inv);
    }
}

// ---------------------------------------------------------------------------
extern "C" void kernel_launch(void* const* d_in, const int* in_sizes, int n_in,
                              void* d_out, int out_size, void* d_ws, size_t ws_size,
                              hipStream_t stream) {
    const int*   positions = (const int*)d_in[0];
    const float* hidden    = (const float*)d_in[1];   // (1024, 2880)
    const float* qkv_w     = (const float*)d_in[2];   // (5120, 2880)
    const float* o_w       = (const float*)d_in[3];   // (2880, 4096)
    const float* sinks     = (const float*)d_in[4];   // (64,)
    float* out = (float*)d_out;                       // (1024, 2880)

    const size_t n_hid  = (size_t)S_LEN * HDIM;       //  2,949,120
    const size_t n_qkv  = (size_t)S_LEN * QKV_N;      //  5,242,880
    const size_t n_attn = (size_t)S_LEN * O_K;        //  4,194,304
    const size_t n_vt   = (size_t)NKV * HD * S_LEN;   //    524,288
    const size_t n_out  = (size_t)S_LEN * HDIM;       //  2,949,120
    const size_t n_qw   = (size_t)QKV_N * HDIM;       // 14,745,600
    const size_t n_ow   = (size_t)HDIM * O_K;         // 11,796,480

    const int SP_Q = 3;   // 2880/3 = 960 = 30 BK-steps, 960 blocks
    const int SP_O = 4;   // 4096/4 = 1024 = 32 BK-steps, 736 blocks

    const size_t need_full =
        (n_hid + SP_Q * n_qkv + n_attn + n_vt + n_qw + n_ow) * sizeof(_Float16);
    const size_t need_mid  = (n_hid + SP_Q * n_qkv + n_attn + n_vt) * sizeof(_Float16);

    if (ws_size >= need_full) {
        // ---- main path: f16 weights, pure-DMA GEMMs ----
        _Float16* hid_h  = (_Float16*)d_ws;
        _Float16* qkvp   = hid_h + n_hid;
        _Float16* attn_h = qkvp + SP_Q * n_qkv;
        _Float16* vt     = attn_h + n_attn;
        _Float16* qw_h   = vt + n_vt;
        _Float16* ow_h   = qw_h + n_qw;
        _Float16* opart  = qkvp;   // SP_O*n_out = 11.8M <= SP_Q*n_qkv = 15.7M

        cvt_all<<<2048, 256, 0, stream>>>(hidden, qkv_w, o_w, hid_h, qw_h, ow_h);
        gemm_ff<_Float16><<<dim3(QKV_N / 128, S_LEN / 128, SP_Q), 256, 0, stream>>>(
            hid_h, qw_h, qkvp, S_LEN, QKV_N, HDIM);
        rope_reduce<<<S_LEN, 256, 0, stream>>>(qkvp, SP_Q, vt, positions);
        attn_mfma<<<dim3(NH, S_LEN / 64), 256, 0, stream>>>(qkvp, vt, sinks, positions, attn_h);
        gemm_ff<_Float16><<<dim3((HDIM + 127) / 128, S_LEN / 128, SP_O), 256, 0, stream>>>(
            attn_h, ow_h, opart, S_LEN, HDIM, O_K);
        o_reduce<<<1024, 256, 0, stream>>>(opart, out, (int)(n_out / 4), SP_O);
    } else if (ws_size >= need_mid) {
        // ---- previous path: fused-cvt B GEMMs ----
        _Float16* hid_h  = (_Float16*)d_ws;
        _Float16* qkvp   = hid_h + n_hid;
        _Float16* attn_h = qkvp + SP_Q * n_qkv;
        _Float16* vt     = attn_h + n_attn;
        _Float16* opart  = qkvp;

        cvt_f32_f16<<<512, 256, 0, stream>>>(hidden, hid_h, (int)(n_hid / 4));
        gemm_f16<_Float16><<<dim3(QKV_N / 128, S_LEN / 128, SP_Q), 256, 0, stream>>>(
            hid_h, qkv_w, qkvp, S_LEN, QKV_N, HDIM);
        rope_reduce<<<S_LEN, 256, 0, stream>>>(qkvp, SP_Q, vt, positions);
        attn_mfma<<<dim3(NH, S_LEN / 64), 256, 0, stream>>>(qkvp, vt, sinks, positions, attn_h);
        gemm_f16<_Float16><<<dim3((HDIM + 127) / 128, S_LEN / 128, SP_O), 256, 0, stream>>>(
            attn_h, o_w, opart, S_LEN, HDIM, O_K);
        o_reduce<<<1024, 256, 0, stream>>>(opart, out, (int)(n_out / 4), SP_O);
    } else {
        // minimal workspace: no split-K, o-proj writes f32 out directly
        _Float16* hid_h  = (_Float16*)d_ws;
        _Float16* qkvp   = hid_h + n_hid;
        _Float16* attn_h = qkvp + n_qkv;
        _Float16* vt     = attn_h + n_attn;

        cvt_f32_f16<<<512, 256, 0, stream>>>(hidden, hid_h, (int)(n_hid / 4));
        gemm_f16<_Float16><<<dim3(QKV_N / 128, S_LEN / 128, 1), 256, 0, stream>>>(
            hid_h, qkv_w, qkvp, S_LEN, QKV_N, HDIM);
        rope_reduce<<<S_LEN, 256, 0, stream>>>(qkvp, 1, vt, positions);
        attn_mfma<<<dim3(NH, S_LEN / 64), 256, 0, stream>>>(qkvp, vt, sinks, positions, attn_h);
        gemm_f16<float><<<dim3((HDIM + 127) / 128, S_LEN / 128, 1), 256, 0, stream>>>(
            attn_h, o_w, out, S_LEN, HDIM, O_K);
    }
}

// Round 3
// 268.549 us; speedup vs baseline: 1.1345x; 1.1111x over previous
//
#include <hip/hip_runtime.h>
#include <hip/hip_bf16.h>
#include <math.h>

// Problem constants
#define S_LEN 1024
#define HDIM  2880
#define NH    64
#define NKV   8
#define HD    64
#define QKV_N ((NH + 2*NKV) * HD)   // 5120
#define O_K   (NH * HD)             // 4096
#define SCALE 0.125f                // HD^-0.5

typedef _Float16 f16x8 __attribute__((ext_vector_type(8)));
typedef _Float16 f16x4 __attribute__((ext_vector_type(4)));
typedef float    f32x4 __attribute__((ext_vector_type(4)));

#define DMA16(GP, LP) __builtin_amdgcn_global_load_lds( \
        (const __attribute__((address_space(1))) void*)(GP), \
        (__attribute__((address_space(3))) void*)(LP), 16, 0, 0)

#define BARRIER() __builtin_amdgcn_s_barrier()
#define WAITV(n)  asm volatile("s_waitcnt vmcnt(" #n ")" ::: "memory")
#define WAITL()   asm volatile("s_waitcnt lgkmcnt(0)" ::: "memory")
#define SCHED0()  __builtin_amdgcn_sched_barrier(0)

// ---------------------------------------------------------------------------
// f32 -> f16 convert (generic; n4 = float4 count)
// ---------------------------------------------------------------------------
__device__ __forceinline__ void cvt4(const float* __restrict__ s,
                                     _Float16* __restrict__ d, int i) {
    const float4 v = ((const float4*)s)[i];
    f16x4 p;
    p[0] = (_Float16)v.x; p[1] = (_Float16)v.y;
    p[2] = (_Float16)v.z; p[3] = (_Float16)v.w;
    ((f16x4*)d)[i] = p;
}

__global__ __launch_bounds__(256) void cvt_f32_f16(const float* __restrict__ src,
                                                   _Float16* __restrict__ dst, int n4) {
    const int stride = gridDim.x * blockDim.x;
    for (int i = blockIdx.x * blockDim.x + threadIdx.x; i < n4; i += stride)
        cvt4(src, dst, i);
}

// One pass: hidden (737280 f4) + qkv_w (3686400 f4) + o_w (2949120 f4)
__global__ __launch_bounds__(256) void cvt_all(const float* __restrict__ h,
                                               const float* __restrict__ qw,
                                               const float* __restrict__ ow,
                                               _Float16* __restrict__ dh,
                                               _Float16* __restrict__ dqw,
                                               _Float16* __restrict__ dow) {
    const int stride = gridDim.x * blockDim.x;
    const int t0 = blockIdx.x * blockDim.x + threadIdx.x;
    for (int i = t0; i < 737280;  i += stride) cvt4(h,  dh,  i);
    for (int i = t0; i < 3686400; i += stride) cvt4(qw, dqw, i);
    for (int i = t0; i < 2949120; i += stride) cvt4(ow, dow, i);
}

// ---------------------------------------------------------------------------
// 256x256 / BK=64 8-wave MFMA GEMM, 4-phase-per-K-tile schedule with counted
// vmcnt.  C[z][M,N](f16) = A[M,Kslice] * B[N,Kslice]^T.
//
// Staging ledger (per wave, uniform order; Sx = 2 DMA ops = one 128x64 half):
//   during tile t: P1 issues S3(t+1)=B-half0 -> buf[(t+1)&1]  (safe: other buf)
//                  P2 issues S4(t+1)=B-half1 -> buf[(t+1)&1]
//                  P3 issues S1(t+2)=A-half0 -> buf[t&1]      (A reads of tile
//                  P4 issues S2(t+2)=A-half1 -> buf[t&1]       t done by P2 bar)
//   P4 wait: vmcnt(4) -> newest 4 (S1,S2(t+2)) may fly; S3,S4(t+1) landed.
//   Barrier after wait makes the guarantee collective (all waves waited).
// Read sets per tile: A-half{wr} in P1+P2; B-half{wc>=2} in P1+P3 -> all four
// halves of tile t must be landed before P1, which the P4 wait+barrier of
// tile t-1 provides.  Prologue: T0 (8 ops) + T1 A-halves (4 ops), vmcnt(4).
// LDS chunk swizzle: 16B chunk j of row r holds global chunk j^(r&7); DMA
// dest linear (pre-swizzled global source), ds_read applies the same XOR.
// ---------------------------------------------------------------------------
__device__ __forceinline__ f16x8 lds_frag(const _Float16* base, int row, int kf) {
    return *(const f16x8*)&base[row * 64 + (kf ^ ((row & 7) << 3))];
}

__device__ __forceinline__ void mfma_quad(f32x4 (&acc)[8][4], const f16x8 (&af)[4][2],
                                          const f16x8 (&bf)[2][2], int mh, int nh) {
    __builtin_amdgcn_s_setprio(1);
#pragma unroll
    for (int q4 = 0; q4 < 4; ++q4)
#pragma unroll
        for (int n2 = 0; n2 < 2; ++n2) {
            f32x4 a = acc[mh * 4 + q4][nh * 2 + n2];
            a = __builtin_amdgcn_mfma_f32_16x16x32_f16(af[q4][0], bf[n2][0], a, 0, 0, 0);
            a = __builtin_amdgcn_mfma_f32_16x16x32_f16(af[q4][1], bf[n2][1], a, 0, 0, 0);
            acc[mh * 4 + q4][nh * 2 + n2] = a;
        }
    __builtin_amdgcn_s_setprio(0);
}

__global__ __launch_bounds__(512, 2) void gemm_8p(const _Float16* __restrict__ A,
                                                  const _Float16* __restrict__ B,
                                                  _Float16* __restrict__ C,
                                                  int M, int N, int K) {
    __shared__ __align__(16) _Float16 sh[65536];   // 128 KB

    const int tid  = threadIdx.x;
    const int lane = tid & 63;
    const int wave = tid >> 6;
    const int wr   = wave >> 2;      // 0..1 (M)
    const int wc   = wave & 3;       // 0..3 (N)
    const int quad = lane >> 4;
    const int fr   = lane & 15;
    const int row0 = blockIdx.y * 256;
    const int col0 = blockIdx.x * 256;

    const int klen = K / (int)gridDim.z;
    const int kb   = (int)blockIdx.z * klen;
    const int NT   = klen / 64;
    _Float16* Cp = C + (size_t)blockIdx.z * M * N;

    // staging maps: half-tile = 128 rows x 64 cols f16 = 1024 x 16B chunks,
    // 2 chunks / thread.  LDS dest linear; global source chunk pre-swizzled.
    int    stDst[2];
    size_t aOff[2][2], bOff[2][2];   // [half][chunk]
#pragma unroll
    for (int r = 0; r < 2; ++r) {
        const int c   = r * 512 + tid;
        const int row = c >> 3;
        const int sw  = ((c & 7) ^ (row & 7)) * 8;
        stDst[r] = (c & ~63) * 8;
#pragma unroll
        for (int h = 0; h < 2; ++h) {
            aOff[h][r] = (size_t)(row0 + h * 128 + row) * K + sw;
            int br = col0 + h * 128 + row; if (br > N - 1) br = N - 1;
            bOff[h][r] = (size_t)br * K + sw;
        }
    }
    const _Float16* Ab = A + kb;
    const _Float16* Bb = B + kb;

#define STAGE2(GB, OFF, LB) do { \
        DMA16((GB) + (OFF)[0], (LB) + stDst[0]); \
        DMA16((GB) + (OFF)[1], (LB) + stDst[1]); } while (0)

    f32x4 acc[8][4] = {};

    // ---- prologue: T0 complete + T1 A-halves; wait T0 ----
    STAGE2(Ab, aOff[0], sh);                    // S1(T0)
    STAGE2(Ab, aOff[1], sh + 8192);             // S2(T0)
    STAGE2(Bb, bOff[0], sh + 32768);            // S3(T0)
    STAGE2(Bb, bOff[1], sh + 32768 + 8192);     // S4(T0)
    if (NT > 1) {
        STAGE2(Ab + 64, aOff[0], sh + 16384);          // S1(T1)
        STAGE2(Ab + 64, aOff[1], sh + 16384 + 8192);   // S2(T1)
        WAITV(4);     // T0's 8 ops landed; T1 A-halves may fly
    } else {
        WAITV(0);
    }
    BARRIER();

    for (int t = 0; t < NT; ++t) {
        _Float16* Ac = sh + ((t & 1) ? 16384 : 0);
        _Float16* Bc = sh + 32768 + ((t & 1) ? 16384 : 0);
        _Float16* Bn = sh + 32768 + ((t & 1) ? 0 : 16384);
        const bool st1 = (t + 1 < NT);
        const bool st2 = (t + 2 < NT);
        const int  k1  = (t + 1) * 64;
        const int  k2  = (t + 2) * 64;

        f16x8 aF0[4][2], aF1[4][2], bF[2][2];

        // ---- P1: quadrant (0,0); read aF0 + bF lo; issue S3(t+1) ----
#pragma unroll
        for (int q4 = 0; q4 < 4; ++q4) {
            const int row = wr * 128 + q4 * 16 + fr;
            aF0[q4][0] = lds_frag(Ac, row, quad * 8);
            aF0[q4][1] = lds_frag(Ac, row, 32 + quad * 8);
        }
#pragma unroll
        for (int n2 = 0; n2 < 2; ++n2) {
            const int row = wc * 64 + n2 * 16 + fr;
            bF[n2][0] = lds_frag(Bc, row, quad * 8);
            bF[n2][1] = lds_frag(Bc, row, 32 + quad * 8);
        }
        if (st1) STAGE2(Bb + k1, bOff[0], Bn);
        BARRIER(); WAITL(); SCHED0();
        mfma_quad(acc, aF0, bF, 0, 0);
        BARRIER();

        // ---- P2: (1,0); read aF1; issue S4(t+1) ----
#pragma unroll
        for (int q4 = 0; q4 < 4; ++q4) {
            const int row = wr * 128 + 64 + q4 * 16 + fr;
            aF1[q4][0] = lds_frag(Ac, row, quad * 8);
            aF1[q4][1] = lds_frag(Ac, row, 32 + quad * 8);
        }
        if (st1) STAGE2(Bb + k1, bOff[1], Bn + 8192);
        BARRIER(); WAITL(); SCHED0();
        mfma_quad(acc, aF1, bF, 1, 0);
        BARRIER();

        // ---- P3: (1,1); read bF hi; issue S1(t+2) into Ac (A reads done) ----
#pragma unroll
        for (int n2 = 0; n2 < 2; ++n2) {
            const int row = wc * 64 + 32 + n2 * 16 + fr;
            bF[n2][0] = lds_frag(Bc, row, quad * 8);
            bF[n2][1] = lds_frag(Bc, row, 32 + quad * 8);
        }
        if (st2) STAGE2(Ab + k2, aOff[0], Ac);
        BARRIER(); WAITL(); SCHED0();
        mfma_quad(acc, aF1, bF, 1, 1);
        BARRIER();

        // ---- P4: (0,1); issue S2(t+2); counted wait covers tile t+1 ----
        if (st2) {
            STAGE2(Ab + k2, aOff[1], Ac + 8192);
            WAITV(4);      // S3,S4(t+1) landed; S1,S2(t+2) may fly
        } else {
            WAITV(0);      // tail: drain everything
        }
        BARRIER(); WAITL(); SCHED0();
        mfma_quad(acc, aF0, bF, 0, 1);
        BARRIER();
    }

    // ---- epilogue via LDS (stride 264), 2 passes over M-halves ----
    __syncthreads();
    _Float16* cbuf = sh;
#pragma unroll
    for (int h = 0; h < 2; ++h) {
        if (wr == h) {
#pragma unroll
            for (int mi = 0; mi < 8; ++mi)
#pragma unroll
                for (int ni = 0; ni < 4; ++ni) {
                    const f32x4 v = acc[mi][ni];
#pragma unroll
                    for (int rr = 0; rr < 4; ++rr)
                        cbuf[(mi * 16 + quad * 4 + rr) * 264 + wc * 64 + ni * 16 + fr] =
                            (_Float16)v[rr];
                }
        }
        __syncthreads();
#pragma unroll
        for (int u = 0; u < 8; ++u) {
            const int c    = u * 512 + tid;
            const int rowL = c >> 5;
            const int ch   = (c & 31) * 8;
            const int col  = col0 + ch;
            if (col < N)
                *(f16x8*)&Cp[(size_t)(row0 + h * 128 + rowL) * N + col] =
                    *(const f16x8*)&cbuf[rowL * 264 + ch];
        }
        __syncthreads();
    }
#undef STAGE2
}

// ---------------------------------------------------------------------------
// 128x128 pure-f16 split-K GEMM (m97 structure) — fallback paths only.
// ---------------------------------------------------------------------------
#define CSTR 68
template<typename CT>
__global__ __launch_bounds__(256) void gemm_ff(const _Float16* __restrict__ A,
                                               const _Float16* __restrict__ B,
                                               CT* __restrict__ C,
                                               int M, int N, int K) {
    __shared__ __align__(16) _Float16 sh[16384];

    const int tid  = threadIdx.x;
    const int lane = tid & 63;
    const int wave = tid >> 6;
    const int wr   = wave >> 1;
    const int wc   = wave & 1;
    const int quad = lane >> 4;
    const int fr   = lane & 15;
    const int ks   = quad * 8;
    const int row0 = blockIdx.y * 128;
    const int col0 = blockIdx.x * 128;

    const int klen   = K / (int)gridDim.z;
    const int kb     = (int)blockIdx.z * klen;
    const int nsteps = klen / 32;
    CT* Cp = C + (size_t)blockIdx.z * M * N;

    const int r0   = tid >> 2;
    const int ch   = (tid & 3) * 8;
    const int dst0 = (tid & ~63) * 8;

    const size_t aoff0 = (size_t)(row0 + r0)      * K;
    const size_t aoff1 = (size_t)(row0 + r0 + 64) * K;
    int bR0 = col0 + r0;      if (bR0 >= N) bR0 = N - 1;
    int bR1 = col0 + r0 + 64; if (bR1 >= N) bR1 = N - 1;
    const size_t boff0 = (size_t)bR0 * K;
    const size_t boff1 = (size_t)bR1 * K;

    f32x4 acc[4][4] = {};

    {
        const int kk = kb + ch;
        DMA16(A + aoff0 + kk, sh + dst0);
        DMA16(A + aoff1 + kk, sh + 2048 + dst0);
        DMA16(B + boff0 + kk, sh + 8192 + dst0);
        DMA16(B + boff1 + kk, sh + 8192 + 2048 + dst0);
    }

    for (int step = 0; step < nsteps; ++step) {
        const int cur = step & 1;
        _Float16* Acur = sh + cur * 4096;
        _Float16* Anxt = sh + (cur ^ 1) * 4096;
        _Float16* Bcur = sh + 8192 + cur * 4096;
        _Float16* Bnxt = sh + 8192 + (cur ^ 1) * 4096;

        __syncthreads();

        if (step + 1 < nsteps) {
            const int k1 = kb + (step + 1) * 32 + ch;
            DMA16(A + aoff0 + k1, Anxt + dst0);
            DMA16(A + aoff1 + k1, Anxt + 2048 + dst0);
            DMA16(B + boff0 + k1, Bnxt + dst0);
            DMA16(B + boff1 + k1, Bnxt + 2048 + dst0);
        }

        f16x8 af[4], bf[4];
#pragma unroll
        for (int mi = 0; mi < 4; ++mi)
            af[mi] = *(const f16x8*)&Acur[(wr * 64 + mi * 16 + fr) * 32 + ks];
#pragma unroll
        for (int ni = 0; ni < 4; ++ni)
            bf[ni] = *(const f16x8*)&Bcur[(wc * 64 + ni * 16 + fr) * 32 + ks];
#pragma unroll
        for (int mi = 0; mi < 4; ++mi)
#pragma unroll
            for (int ni = 0; ni < 4; ++ni)
                acc[mi][ni] = __builtin_amdgcn_mfma_f32_16x16x32_f16(
                    af[mi], bf[ni], acc[mi][ni], 0, 0, 0);
    }

#pragma unroll
    for (int p = 0; p < 2; ++p) {
        __syncthreads();
        if (wc == p) {
#pragma unroll
            for (int mi = 0; mi < 4; ++mi)
#pragma unroll
                for (int ni = 0; ni < 4; ++ni) {
                    const f32x4 v = acc[mi][ni];
#pragma unroll
                    for (int r = 0; r < 4; ++r)
                        sh[(wr * 64 + mi * 16 + quad * 4 + r) * CSTR + ni * 16 + fr] =
                            (_Float16)v[r];
                }
        }
        __syncthreads();
#pragma unroll
        for (int it = 0; it < 4; ++it) {
            const int id  = it * 256 + tid;
            const int row = id >> 3;
            const int chh = (id & 7) * 8;
            const int col = col0 + p * 64 + chh;
            if (col < N) {
                const f16x4 lo = *(const f16x4*)&sh[row * CSTR + chh];
                const f16x4 hi = *(const f16x4*)&sh[row * CSTR + chh + 4];
                if constexpr (sizeof(CT) == 2) {
                    f16x8 v;
                    v[0]=lo[0]; v[1]=lo[1]; v[2]=lo[2]; v[3]=lo[3];
                    v[4]=hi[0]; v[5]=hi[1]; v[6]=hi[2]; v[7]=hi[3];
                    *(f16x8*)&Cp[(size_t)(row0 + row) * N + col] = v;
                } else {
                    float4 v0 = make_float4((float)lo[0], (float)lo[1],
                                            (float)lo[2], (float)lo[3]);
                    float4 v1 = make_float4((float)hi[0], (float)hi[1],
                                            (float)hi[2], (float)hi[3]);
                    *(float4*)&Cp[(size_t)(row0 + row) * N + col]     = v0;
                    *(float4*)&Cp[(size_t)(row0 + row) * N + col + 4] = v1;
                }
            }
        }
    }
}

// ---------------------------------------------------------------------------
// Fallback GEMM (fused f32->f16 B conversion) — minimal-workspace path.
// ---------------------------------------------------------------------------
template<typename CT>
__global__ __launch_bounds__(256) void gemm_f16(const _Float16* __restrict__ A,
                                                const float* __restrict__ B,
                                                CT* __restrict__ C,
                                                int M, int N, int K) {
    __shared__ __align__(16) _Float16 sh[16384];

    const int tid  = threadIdx.x;
    const int lane = tid & 63;
    const int wave = tid >> 6;
    const int wr   = wave >> 1;
    const int wc   = wave & 1;
    const int quad = lane >> 4;
    const int fr   = lane & 15;
    const int ks   = quad * 8;
    const int row0 = blockIdx.y * 128;
    const int col0 = blockIdx.x * 128;

    const int klen   = K / (int)gridDim.z;
    const int kb     = (int)blockIdx.z * klen;
    const int nsteps = klen / 32;
    CT* Cp = C + (size_t)blockIdx.z * M * N;

    const int a_cbase0 = wave * 64;
    const int a_ci0 = a_cbase0 + lane;
    const int a_r0 = a_ci0 >> 2, a_ch0 = a_ci0 & 3;
    const int a_cbase1 = 256 + wave * 64;
    const int a_ci1 = a_cbase1 + lane;
    const int a_r1 = a_ci1 >> 2, a_ch1 = a_ci1 & 3;
    int b_r[4], b_ch[4];
#pragma unroll
    for (int it = 0; it < 4; ++it) {
        const int c4 = it * 256 + tid;
        b_r[it]  = c4 >> 3;
        b_ch[it] = (c4 & 7) << 2;
    }

    float4 breg[4];
    f32x4 acc[4][4] = {};

    {
        const _Float16* gp0 = A + (size_t)(row0 + a_r0) * K + kb + a_ch0 * 8;
        DMA16(gp0, sh + (size_t)a_cbase0 * 8);
        const _Float16* gp1 = A + (size_t)(row0 + a_r1) * K + kb + a_ch1 * 8;
        DMA16(gp1, sh + (size_t)a_cbase1 * 8);
#pragma unroll
        for (int it = 0; it < 4; ++it) {
            int brow = col0 + b_r[it];
            if (brow >= N) brow = N - 1;
            breg[it] = *(const float4*)&B[(size_t)brow * K + kb + b_ch[it]];
        }
        _Float16* Bs0 = sh + 8192;
#pragma unroll
        for (int it = 0; it < 4; ++it) {
            f16x4 p;
            p[0] = (_Float16)breg[it].x; p[1] = (_Float16)breg[it].y;
            p[2] = (_Float16)breg[it].z; p[3] = (_Float16)breg[it].w;
            *(f16x4*)&Bs0[b_r[it] * 32 + b_ch[it]] = p;
        }
    }

    for (int step = 0; step < nsteps; ++step) {
        const int cur = step & 1;
        const int nxt = cur ^ 1;
        _Float16* Acur = sh + cur * 4096;
        _Float16* Anxt = sh + nxt * 4096;
        _Float16* Bcur = sh + 8192 + cur * 4096;
        _Float16* Bnxt = sh + 8192 + nxt * 4096;

        __syncthreads();

        const bool more = (step + 1 < nsteps);
        if (more) {
            const int k1 = kb + (step + 1) * 32;
            const _Float16* gp0 = A + (size_t)(row0 + a_r0) * K + k1 + a_ch0 * 8;
            DMA16(gp0, Anxt + (size_t)a_cbase0 * 8);
            const _Float16* gp1 = A + (size_t)(row0 + a_r1) * K + k1 + a_ch1 * 8;
            DMA16(gp1, Anxt + (size_t)a_cbase1 * 8);
#pragma unroll
            for (int it = 0; it < 4; ++it) {
                int brow = col0 + b_r[it];
                if (brow >= N) brow = N - 1;
                breg[it] = *(const float4*)&B[(size_t)brow * K + k1 + b_ch[it]];
            }
        }

        f16x8 af[4], bfr[4];
#pragma unroll
        for (int mi = 0; mi < 4; ++mi)
            af[mi] = *(const f16x8*)&Acur[(wr * 64 + mi * 16 + fr) * 32 + ks];
#pragma unroll
        for (int ni = 0; ni < 4; ++ni)
            bfr[ni] = *(const f16x8*)&Bcur[(wc * 64 + ni * 16 + fr) * 32 + ks];
#pragma unroll
        for (int mi = 0; mi < 4; ++mi)
#pragma unroll
            for (int ni = 0; ni < 4; ++ni)
                acc[mi][ni] = __builtin_amdgcn_mfma_f32_16x16x32_f16(
                    af[mi], bfr[ni], acc[mi][ni], 0, 0, 0);

        if (more) {
#pragma unroll
            for (int it = 0; it < 4; ++it) {
                f16x4 p;
                p[0] = (_Float16)breg[it].x; p[1] = (_Float16)breg[it].y;
                p[2] = (_Float16)breg[it].z; p[3] = (_Float16)breg[it].w;
                *(f16x4*)&Bnxt[b_r[it] * 32 + b_ch[it]] = p;
            }
        }
    }

#pragma unroll
    for (int p = 0; p < 2; ++p) {
        __syncthreads();
        if (wc == p) {
#pragma unroll
            for (int mi = 0; mi < 4; ++mi)
#pragma unroll
                for (int ni = 0; ni < 4; ++ni) {
                    const f32x4 v = acc[mi][ni];
#pragma unroll
                    for (int r = 0; r < 4; ++r)
                        sh[(wr * 64 + mi * 16 + quad * 4 + r) * CSTR + ni * 16 + fr] =
                            (_Float16)v[r];
                }
        }
        __syncthreads();
#pragma unroll
        for (int it = 0; it < 4; ++it) {
            const int id  = it * 256 + tid;
            const int row = id >> 3;
            const int chh = (id & 7) * 8;
            const int col = col0 + p * 64 + chh;
            if (col < N) {
                const f16x4 lo = *(const f16x4*)&sh[row * CSTR + chh];
                const f16x4 hi = *(const f16x4*)&sh[row * CSTR + chh + 4];
                if constexpr (sizeof(CT) == 2) {
                    f16x8 v;
                    v[0]=lo[0]; v[1]=lo[1]; v[2]=lo[2]; v[3]=lo[3];
                    v[4]=hi[0]; v[5]=hi[1]; v[6]=hi[2]; v[7]=hi[3];
                    *(f16x8*)&Cp[(size_t)(row0 + row) * N + col] = v;
                } else {
                    float4 v0 = make_float4((float)lo[0], (float)lo[1],
                                            (float)lo[2], (float)lo[3]);
                    float4 v1 = make_float4((float)hi[0], (float)hi[1],
                                            (float)hi[2], (float)hi[3]);
                    *(float4*)&Cp[(size_t)(row0 + row) * N + col]     = v0;
                    *(float4*)&Cp[(size_t)(row0 + row) * N + col + 4] = v1;
                }
            }
        }
    }
}

// ---------------------------------------------------------------------------
// Fused: sum nsplit f16 qkv partials -> rope q,k -> write f16 into partial 0;
// also emit V transposed as vt[d 512][s 1024]. One block per position.
// ---------------------------------------------------------------------------
__global__ __launch_bounds__(256) void rope_reduce(_Float16* __restrict__ parts,
                                                   int nsplit,
                                                   _Float16* __restrict__ vt,
                                                   const int* __restrict__ positions) {
    __shared__ float buf[QKV_N];   // 20 KB
    const int s   = blockIdx.x;
    const int tid = threadIdx.x;
    const size_t PSTR = (size_t)S_LEN * QKV_N;

    for (int c = tid; c < QKV_N / 4; c += 256) {
        float4 a = make_float4(0.f, 0.f, 0.f, 0.f);
        for (int j = 0; j < nsplit; ++j) {
            const f16x4 v = ((const f16x4*)(parts + j * PSTR + (size_t)s * QKV_N))[c];
            a.x += (float)v[0]; a.y += (float)v[1];
            a.z += (float)v[2]; a.w += (float)v[3];
        }
        ((float4*)buf)[c] = a;
    }
    __syncthreads();

    const float pos = (float)positions[s];
    _Float16* orow = parts + (size_t)s * QKV_N;   // write into partial 0
    for (int w = tid; w < 72 * 32; w += 256) {
        const int h = w >> 5;
        const int t = w & 31;
        const float inv_freq = exp2f(-(float)t * (13.287712379549449f / 32.0f));
        const float ang = pos * inv_freq;
        float sn, cs;
        sincosf(ang, &sn, &cs);
        const float x1 = buf[h * 64 + t];
        const float x2 = buf[h * 64 + t + 32];
        orow[h * 64 + t]      = (_Float16)(x1 * cs - x2 * sn);
        orow[h * 64 + t + 32] = (_Float16)(x2 * cs + x1 * sn);
    }
    // V -> vt (transposed), source cols 4608..5119
    for (int c = tid; c < NKV * HD; c += 256)
        vt[(size_t)c * S_LEN + s] = (_Float16)buf[(NH + NKV) * HD + c];
}

// ---------------------------------------------------------------------------
// o-proj partial reduce: out(f32) = sum of nsplit f16 partials
// ---------------------------------------------------------------------------
__global__ __launch_bounds__(256) void o_reduce(const _Float16* __restrict__ parts,
                                                float* __restrict__ out,
                                                int n4, int nsplit) {
    const size_t PSTR = (size_t)S_LEN * HDIM;
    const int stride = gridDim.x * blockDim.x;
    for (int i = blockIdx.x * blockDim.x + threadIdx.x; i < n4; i += stride) {
        float4 a = make_float4(0.f, 0.f, 0.f, 0.f);
        for (int j = 0; j < nsplit; ++j) {
            const f16x4 v = ((const f16x4*)(parts + j * PSTR))[i];
            a.x += (float)v[0]; a.y += (float)v[1];
            a.z += (float)v[2]; a.w += (float)v[3];
        }
        ((float4*)out)[i] = a;
    }
}

// ---------------------------------------------------------------------------
// MFMA flash attention, double-buffered K/V staging (single barrier / tile).
// ---------------------------------------------------------------------------
#define LSTR 72
__global__ __launch_bounds__(256) void attn_mfma(const _Float16* __restrict__ qkv,
                                                 const _Float16* __restrict__ vt,
                                                 const float* __restrict__ sinks,
                                                 const int* __restrict__ positions,
                                                 _Float16* __restrict__ attn_out) {
    __shared__ __align__(16) _Float16 Ks[2][64 * LSTR];
    __shared__ __align__(16) _Float16 Vs[2][64 * LSTR];
    __shared__ __align__(16) _Float16 Ps[64 * LSTR];

    const int tid  = threadIdx.x;
    const int lane = tid & 63;
    const int wave = tid >> 6;
    const int fr   = lane & 15;
    const int quad = lane >> 4;
    const int ks8  = quad * 8;
    const int n    = blockIdx.x;
    const int qt   = (int)gridDim.y - 1 - (int)blockIdx.y;   // heavy tiles first
    const int g    = n >> 3;

    int st_r[2], st_o[2];
#pragma unroll
    for (int it = 0; it < 2; ++it) {
        const int c = it * 256 + tid;
        st_r[it] = c >> 3;
        st_o[it] = (c & 7) * 8;
    }

    const _Float16* qrow = qkv + (size_t)(qt * 64 + wave * 16 + fr) * QKV_N + n * HD;
    const f16x8 a_q0 = *(const f16x8*)&qrow[ks8];
    const f16x8 a_q1 = *(const f16x8*)&qrow[32 + ks8];

    int pq[4];
#pragma unroll
    for (int r = 0; r < 4; ++r)
        pq[r] = positions[qt * 64 + wave * 16 + quad * 4 + r];

    const float sinkv = sinks[n];
    float m[4], l[4];
    f32x4 o[4] = {};
#pragma unroll
    for (int r = 0; r < 4; ++r) { m[r] = sinkv; l[r] = 1.0f; }

    f16x8 kreg[2], vreg[2];
    {
        const _Float16* Kg = qkv + (size_t)0 * QKV_N + NH * HD + g * HD;
        const _Float16* Vg = vt + (size_t)(g * HD) * S_LEN;
#pragma unroll
        for (int it = 0; it < 2; ++it) {
            kreg[it] = *(const f16x8*)&Kg[(size_t)st_r[it] * QKV_N + st_o[it]];
            vreg[it] = *(const f16x8*)&Vg[(size_t)st_r[it] * S_LEN + st_o[it]];
        }
#pragma unroll
        for (int it = 0; it < 2; ++it) {
            *(f16x8*)&Ks[0][st_r[it] * LSTR + st_o[it]] = kreg[it];
            *(f16x8*)&Vs[0][st_r[it] * LSTR + st_o[it]] = vreg[it];
        }
    }

    for (int kt = 0; kt <= qt; ++kt) {
        const int cur = kt & 1;
        const int nxt = cur ^ 1;
        __syncthreads();

        const bool more = (kt < qt);
        if (more) {
            const _Float16* Kg = qkv + (size_t)((kt + 1) * 64) * QKV_N + NH * HD + g * HD;
            const _Float16* Vg = vt + (size_t)(g * HD) * S_LEN + (kt + 1) * 64;
#pragma unroll
            for (int it = 0; it < 2; ++it) {
                kreg[it] = *(const f16x8*)&Kg[(size_t)st_r[it] * QKV_N + st_o[it]];
                vreg[it] = *(const f16x8*)&Vg[(size_t)st_r[it] * S_LEN + st_o[it]];
            }
        }

        f32x4 s[4] = {};
#pragma unroll
        for (int nt = 0; nt < 4; ++nt) {
            const f16x8 b0 = *(const f16x8*)&Ks[cur][(nt * 16 + fr) * LSTR + ks8];
            s[nt] = __builtin_amdgcn_mfma_f32_16x16x32_f16(a_q0, b0, s[nt], 0, 0, 0);
            const f16x8 b1 = *(const f16x8*)&Ks[cur][(nt * 16 + fr) * LSTR + 32 + ks8];
            s[nt] = __builtin_amdgcn_mfma_f32_16x16x32_f16(a_q1, b1, s[nt], 0, 0, 0);
        }

        const bool diag = (kt == qt);
        int pk[4];
        if (diag) {
#pragma unroll
            for (int nt = 0; nt < 4; ++nt) pk[nt] = positions[qt * 64 + nt * 16 + fr];
        }
#pragma unroll
        for (int nt = 0; nt < 4; ++nt)
#pragma unroll
            for (int r = 0; r < 4; ++r) {
                float sv = s[nt][r] * SCALE;
                if (diag && pk[nt] > pq[r]) sv = -3.0e38f;
                s[nt][r] = sv;
            }

#pragma unroll
        for (int r = 0; r < 4; ++r) {
            float tm = fmaxf(fmaxf(s[0][r], s[1][r]), fmaxf(s[2][r], s[3][r]));
            tm = fmaxf(tm, __shfl_xor(tm, 1, 64));
            tm = fmaxf(tm, __shfl_xor(tm, 2, 64));
            tm = fmaxf(tm, __shfl_xor(tm, 4, 64));
            tm = fmaxf(tm, __shfl_xor(tm, 8, 64));
            const float nm = fmaxf(m[r], tm);
            const float alpha = __expf(m[r] - nm);
            float rs = 0.0f;
#pragma unroll
            for (int nt = 0; nt < 4; ++nt) {
                const float p = __expf(s[nt][r] - nm);
                s[nt][r] = p;
                rs += p;
            }
            rs += __shfl_xor(rs, 1, 64);
            rs += __shfl_xor(rs, 2, 64);
            rs += __shfl_xor(rs, 4, 64);
            rs += __shfl_xor(rs, 8, 64);
            l[r] = l[r] * alpha + rs;
            m[r] = nm;
#pragma unroll
            for (int nt = 0; nt < 4; ++nt) o[nt][r] *= alpha;
        }

#pragma unroll
        for (int nt = 0; nt < 4; ++nt)
#pragma unroll
            for (int r = 0; r < 4; ++r)
                Ps[(wave * 16 + quad * 4 + r) * LSTR + nt * 16 + fr] = (_Float16)s[nt][r];
        __threadfence_block();

#pragma unroll
        for (int k2 = 0; k2 < 2; ++k2) {
            const f16x8 ap = *(const f16x8*)&Ps[(wave * 16 + fr) * LSTR + k2 * 32 + ks8];
#pragma unroll
            for (int nt = 0; nt < 4; ++nt) {
                const f16x8 bv = *(const f16x8*)&Vs[cur][(nt * 16 + fr) * LSTR + k2 * 32 + ks8];
                o[nt] = __builtin_amdgcn_mfma_f32_16x16x32_f16(ap, bv, o[nt], 0, 0, 0);
            }
        }

        if (more) {
#pragma unroll
            for (int it = 0; it < 2; ++it) {
                *(f16x8*)&Ks[nxt][st_r[it] * LSTR + st_o[it]] = kreg[it];
                *(f16x8*)&Vs[nxt][st_r[it] * LSTR + st_o[it]] = vreg[it];
            }
        }
    }

#pragma unroll
    for (int r = 0; r < 4; ++r) {
        const float inv = 1.0f / l[r];
        const size_t row = (size_t)(qt * 64 + wave * 16 + quad * 4 + r);
#pragma unroll
        for (int nt = 0; nt < 4; ++nt)
            attn_out[row * O_K + n * HD + nt * 16 + fr] = (_Float16)(o[nt][r] * inv);
    }
}

// ---------------------------------------------------------------------------
extern "C" void kernel_launch(void* const* d_in, const int* in_sizes, int n_in,
                              void* d_out, int out_size, void* d_ws, size_t ws_size,
                              hipStream_t stream) {
    const int*   positions = (const int*)d_in[0];
    const float* hidden    = (const float*)d_in[1];   // (1024, 2880)
    const float* qkv_w     = (const float*)d_in[2];   // (5120, 2880)
    const float* o_w       = (const float*)d_in[3];   // (2880, 4096)
    const float* sinks     = (const float*)d_in[4];   // (64,)
    float* out = (float*)d_out;                       // (1024, 2880)

    const size_t n_hid  = (size_t)S_LEN * HDIM;       //  2,949,120
    const size_t n_qkv  = (size_t)S_LEN * QKV_N;      //  5,242,880
    const size_t n_attn = (size_t)S_LEN * O_K;        //  4,194,304
    const size_t n_vt   = (size_t)NKV * HD * S_LEN;   //    524,288
    const size_t n_out  = (size_t)S_LEN * HDIM;       //  2,949,120
    const size_t n_qw   = (size_t)QKV_N * HDIM;       // 14,745,600
    const size_t n_ow   = (size_t)HDIM * O_K;         // 11,796,480

    const int SP_Q = 3;   // 2880/3 = 960 = 15 BK64-tiles, 240 blocks
    const int SP_O = 4;   // 4096/4 = 1024 = 16 BK64-tiles, 192 blocks

    const size_t need_full =
        (n_hid + SP_Q * n_qkv + n_attn + n_vt + n_qw + n_ow) * sizeof(_Float16);
    const size_t need_mid  = (n_hid + SP_Q * n_qkv + n_attn + n_vt) * sizeof(_Float16);

    if (ws_size >= need_full) {
        // ---- main path: f16 weights, 256^2 4-phase GEMMs ----
        _Float16* hid_h  = (_Float16*)d_ws;
        _Float16* qkvp   = hid_h + n_hid;
        _Float16* attn_h = qkvp + SP_Q * n_qkv;
        _Float16* vt     = attn_h + n_attn;
        _Float16* qw_h   = vt + n_vt;
        _Float16* ow_h   = qw_h + n_qw;
        _Float16* opart  = qkvp;   // SP_O*n_out = 11.8M <= SP_Q*n_qkv = 15.7M

        cvt_all<<<2048, 256, 0, stream>>>(hidden, qkv_w, o_w, hid_h, qw_h, ow_h);
        gemm_8p<<<dim3(QKV_N / 256, S_LEN / 256, SP_Q), 512, 0, stream>>>(
            hid_h, qw_h, qkvp, S_LEN, QKV_N, HDIM);
        rope_reduce<<<S_LEN, 256, 0, stream>>>(qkvp, SP_Q, vt, positions);
        attn_mfma<<<dim3(NH, S_LEN / 64), 256, 0, stream>>>(qkvp, vt, sinks, positions, attn_h);
        gemm_8p<<<dim3((HDIM + 255) / 256, S_LEN / 256, SP_O), 512, 0, stream>>>(
            attn_h, ow_h, opart, S_LEN, HDIM, O_K);
        o_reduce<<<1024, 256, 0, stream>>>(opart, out, (int)(n_out / 4), SP_O);
    } else if (ws_size >= need_mid) {
        // ---- mid path: fused-cvt B GEMMs (128^2) ----
        _Float16* hid_h  = (_Float16*)d_ws;
        _Float16* qkvp   = hid_h + n_hid;
        _Float16* attn_h = qkvp + SP_Q * n_qkv;
        _Float16* vt     = attn_h + n_attn;
        _Float16* opart  = qkvp;

        cvt_f32_f16<<<512, 256, 0, stream>>>(hidden, hid_h, (int)(n_hid / 4));
        gemm_f16<_Float16><<<dim3(QKV_N / 128, S_LEN / 128, SP_Q), 256, 0, stream>>>(
            hid_h, qkv_w, qkvp, S_LEN, QKV_N, HDIM);
        rope_reduce<<<S_LEN, 256, 0, stream>>>(qkvp, SP_Q, vt, positions);
        attn_mfma<<<dim3(NH, S_LEN / 64), 256, 0, stream>>>(qkvp, vt, sinks, positions, attn_h);
        gemm_f16<_Float16><<<dim3((HDIM + 127) / 128, S_LEN / 128, SP_O), 256, 0, stream>>>(
            attn_h, o_w, opart, S_LEN, HDIM, O_K);
        o_reduce<<<1024, 256, 0, stream>>>(opart, out, (int)(n_out / 4), SP_O);
    } else {
        // minimal workspace: no split-K, o-proj writes f32 out directly
        _Float16* hid_h  = (_Float16*)d_ws;
        _Float16* qkvp   = hid_h + n_hid;
        _Float16* attn_h = qkvp + n_qkv;
        _Float16* vt     = attn_h + n_attn;

        cvt_f32_f16<<<512, 256, 0, stream>>>(hidden, hid_h, (int)(n_hid / 4));
        gemm_f16<_Float16><<<dim3(QKV_N / 128, S_LEN / 128, 1), 256, 0, stream>>>(
            hid_h, qkv_w, qkvp, S_LEN, QKV_N, HDIM);
        rope_reduce<<<S_LEN, 256, 0, stream>>>(qkvp, 1, vt, positions);
        attn_mfma<<<dim3(NH, S_LEN / 64), 256, 0, stream>>>(qkvp, vt, sinks, positions, attn_h);
        gemm_f16<float><<<dim3((HDIM + 127) / 128, S_LEN / 128, 1), 256, 0, stream>>>(
            attn_h, o_w, out, S_LEN, HDIM, O_K);
    }
}